// Round 1
// baseline (23616.977 us; speedup 1.0000x reference)
//
#include <hip/hip_runtime.h>
#include <math.h>

// Problem constants (fixed by the reference)
#define Bb 32
#define Tt 64
#define Pp 2048
#define Dd 32
#define NOBS 16

// ---------------------------------------------------------------------------
// Threefry-2x32-20 (exact JAX semantics, threefry_partitionable=True default):
//   base  = key(42)            -> (0, 42)
//   kt    = fold_in(base, t)   -> TF(base, (0, t))       [both words = new key]
//   k_res, k_noise = split(kt) -> TF(kt, (0,0)), TF(kt, (0,1))
//   draw i (32-bit)            -> x0 ^ x1 of TF(k, (hi32(i), lo32(i)))
// ---------------------------------------------------------------------------
__device__ __forceinline__ unsigned rotl32(unsigned v, int r) {
  return (v << r) | (v >> (32 - r));
}

__device__ __forceinline__ void tf2x32(unsigned k0, unsigned k1,
                                       unsigned c0, unsigned c1,
                                       unsigned& r0, unsigned& r1) {
  unsigned k2 = k0 ^ k1 ^ 0x1BD11BDAu;
  unsigned x0 = c0 + k0;
  unsigned x1 = c1 + k1;
#define TF_ROUND(R) { x0 += x1; x1 = rotl32(x1, (R)); x1 ^= x0; }
  TF_ROUND(13) TF_ROUND(15) TF_ROUND(26) TF_ROUND(6)
  x0 += k1; x1 += k2 + 1u;
  TF_ROUND(17) TF_ROUND(29) TF_ROUND(16) TF_ROUND(24)
  x0 += k2; x1 += k0 + 2u;
  TF_ROUND(13) TF_ROUND(15) TF_ROUND(26) TF_ROUND(6)
  x0 += k0; x1 += k1 + 3u;
  TF_ROUND(17) TF_ROUND(29) TF_ROUND(16) TF_ROUND(24)
  x0 += k1; x1 += k2 + 4u;
  TF_ROUND(13) TF_ROUND(15) TF_ROUND(26) TF_ROUND(6)
  x0 += k2; x1 += k0 + 5u;
#undef TF_ROUND
  r0 = x0; r1 = x1;
}

// Correctly-rounded f32 log/exp via double libm.
__device__ __forceinline__ float logf_cr(float x) { return (float)log((double)x); }
__device__ __forceinline__ float expf_cr(float x) { return (float)exp((double)x); }

// Exact gumbel, bit-faithful to jax.random.gumbel:
// u = bitcast(bits>>9 | 1.0f) - 1; u = u*1 + tiny (== max(tiny, .)); g=-ln(-ln u)
// Hard range (all 2^23 mantissas): g in [-4.46967, +15.94239].
__device__ __forceinline__ float gumbel_exact(unsigned bits) {
  float fl = __uint_as_float(0x3f800000u | (bits >> 9)) - 1.0f;  // exact
  float u  = __fadd_rn(fl, 1.17549435e-38f);
  float il = logf_cr(u);             // in [-87.34, -5.96e-8], never 0
  return -logf_cr(-il);
}

// Fast screening gumbel via hw v_log_f32.  g = 0.36651292 - ln2*log2(-log2 u).
// Guard: u within 2^-13 of 1 -> exact fallback (rate 2^-13, negligible).
// |g_fast - g_exact| <= ~1e-3 << margin 0.125.
__device__ __forceinline__ float gumbel_fast(unsigned bits) {
  float fl = __uint_as_float(0x3f800000u | (bits >> 9)) - 1.0f;
  if (fl > 0.999877929f) return gumbel_exact(bits);
  float u  = fl + 1.17549435e-38f;
  float t  = -__log2f(u);            // > 0
  return fmaf(-0.69314718056f, __log2f(t), 0.3665129205816643f);
}

// XLA ErfInv32 (Giles poly) with XLA EmitLog1p (|x|<1e-4 small branch).
__device__ __forceinline__ float erfinv_xla(float x) {
  float nxx = __fmul_rn(-x, x);
  float l1p;
  if (fabsf(nxx) < 1e-4f) {
    l1p = __fmul_rn(__fadd_rn(__fmul_rn(-0.5f, nxx), 1.0f), nxx);
  } else {
    l1p = logf_cr(__fadd_rn(1.0f, nxx));
  }
  float w = -l1p;
  float p;
  if (w < 5.0f) {
    float ww = __fsub_rn(w, 2.5f);
    p = 2.81022636e-08f;
    p = __fadd_rn(3.43273939e-07f,  __fmul_rn(p, ww));
    p = __fadd_rn(-3.5233877e-06f,  __fmul_rn(p, ww));
    p = __fadd_rn(-4.39150654e-06f, __fmul_rn(p, ww));
    p = __fadd_rn(0.00021858087f,   __fmul_rn(p, ww));
    p = __fadd_rn(-0.00125372503f,  __fmul_rn(p, ww));
    p = __fadd_rn(-0.00417768164f,  __fmul_rn(p, ww));
    p = __fadd_rn(0.246640727f,     __fmul_rn(p, ww));
    p = __fadd_rn(1.50140941f,      __fmul_rn(p, ww));
  } else {
    float ww = __fsub_rn(sqrtf(w), 3.0f);
    p = -0.000200214257f;
    p = __fadd_rn(0.000100950558f,  __fmul_rn(p, ww));
    p = __fadd_rn(0.00134934322f,   __fmul_rn(p, ww));
    p = __fadd_rn(-0.00367342844f,  __fmul_rn(p, ww));
    p = __fadd_rn(0.00573950773f,   __fmul_rn(p, ww));
    p = __fadd_rn(-0.0076224613f,   __fmul_rn(p, ww));
    p = __fadd_rn(0.00943887047f,   __fmul_rn(p, ww));
    p = __fadd_rn(1.00167406f,      __fmul_rn(p, ww));
    p = __fadd_rn(2.83297682f,      __fmul_rn(p, ww));
  }
  return __fmul_rn(p, x);
}

// ---------------------------------------------------------------------------
// Kernel A: logsumexp (exact numpy pairwise order) + ACTIVE-SET build.
// A particle j can win argmax_j(w_j + g_j) only if
//   w_j >= w_max - (g_max - g_min) = w_max - 20.41206   (g bounds above).
// thr = w_max - 20.45 (0.038 slack >> f32 rounding slop).  Active entries
// {w_norm_j, j} are compacted into d_ws (order-free: cat tie-breaks on j).
// Normalized weights are NOT written back to wseq anymore (cat reads the
// active list instead); wseq[b,t,:] is later filled with logw by fwd.
// ---------------------------------------------------------------------------
__global__ __launch_bounds__(256) void norm_kernel(const float* __restrict__ wseq,
                                                   float2* __restrict__ act,
                                                   int* __restrict__ counts,
                                                   int t) {
  __shared__ float lw[Pp];
  __shared__ float red[256];
  __shared__ float rr[128];
  __shared__ float sh_mx, sh_lse;
  __shared__ int s_cnt;
  int b = blockIdx.x;
  int tid = threadIdx.x;
  const float* src = wseq + ((size_t)b * Tt + (t - 1)) * Pp;  // valid t>0
  float loc[8];
  for (int k = 0; k < 8; ++k) {
    int j = tid + k * 256;
    float v = (t == 0) ? 0.00048828125f : src[j];   // w0 = 1/2048
    lw[j] = v; loc[k] = v;
  }
  float m = loc[0];
  for (int k = 1; k < 8; ++k) m = fmaxf(m, loc[k]);
  red[tid] = m;
  __syncthreads();
  if (tid == 0) {                      // max is order-free; keep it simple
    float mm = red[0];
    for (int k = 1; k < 256; ++k) mm = fmaxf(mm, red[k]);
    sh_mx = mm;
  }
  __syncthreads();
  float mx = sh_mx;
  if (tid < 128) {                     // numpy leaf chains (16 terms, seq)
    int base = (tid >> 3) * 128 + (tid & 7);
    float r = expf_cr(__fsub_rn(lw[base], mx));
    for (int i = 1; i < 16; ++i)
      r = __fadd_rn(r, expf_cr(__fsub_rn(lw[base + 8 * i], mx)));
    rr[tid] = r;
  }
  __syncthreads();
  if (tid < 64) {                      // adjacent binary tree (exact order)
    float s = __fadd_rn(rr[2 * tid], rr[2 * tid + 1]);
    for (int off = 1; off <= 32; off <<= 1)
      s = __fadd_rn(s, __shfl_xor(s, off));   // commutative -> same bits
    if (tid == 0) sh_lse = __fadd_rn(logf_cr(s), mx);
  }
  if (tid == 0) s_cnt = 0;
  __syncthreads();
  float lse = sh_lse;
  // w_norm_max = mx - lse (>= -ln(2048) > -50, never clipped)
  float thr = __fsub_rn(__fsub_rn(mx, lse), 20.45f);
  float2* abase = act + (size_t)b * Pp;
  for (int k = 0; k < 8; ++k) {
    int j = tid + k * 256;
    float wn = fmaxf(__fsub_rn(lw[j], lse), -50.0f);
    if (wn >= thr) {                   // thr > -50 always -> clip irrelevant
      int pos = atomicAdd(&s_cnt, 1);
      abase[pos] = make_float2(wn, __int_as_float(j));
    }
  }
  __syncthreads();
  if (tid == 0) counts[b] = s_cnt;
}

// ---------------------------------------------------------------------------
// Kernel B: jax.random.categorical(k_res, w, shape=(P,B)).T — gumbel shape
// (P,B,P), flat m=(i*B+b)*P+j, argmax over j, first-occurrence ties.
// Now iterates ONLY the active set (argmax provably inside it).  Screened:
// pass 1 fast hw-log gumbels over active chunks (static 32-chunk unroll with
// wave-uniform skip so vf[] stays in registers), wave max, then exact CR
// re-eval of candidates within margin 0.125.  One wave per sample i.
// Tie-break: explicit (v, j) lexicographic (list order is arbitrary).
// Result idx stashed as int bits in pseq[b,t,i,0].
// ---------------------------------------------------------------------------
__global__ __launch_bounds__(256) void cat_kernel(const float2* __restrict__ act,
                                                  const int* __restrict__ counts,
                                                  float* __restrict__ pseq,
                                                  int t) {
  __shared__ float2 alds[Pp];
  int b = blockIdx.y;
  int tid = threadIdx.x;
  int n_act = counts[b];
  int nchunk = (n_act + 63) >> 6;       // >= 1 (max particle always active)
  int tot = nchunk << 6;
  const float2* abase = act + (size_t)b * Pp;
  for (int k = tid; k < tot; k += 256)  // sentinel pad: w=-INF -> v=-INF
    alds[k] = (k < n_act) ? abase[k]
                          : make_float2(-INFINITY, __int_as_float(0x7fffffff));
  __syncthreads();

  unsigned kt0, kt1, kr0, kr1;
  tf2x32(0u, 42u, 0u, (unsigned)t, kt0, kt1);   // fold_in(key(42), t)
  tf2x32(kt0, kt1, 0u, 0u, kr0, kr1);           // split -> k_res

  int wave = tid >> 6, lane = tid & 63;
  int i = blockIdx.x * 4 + wave;
  unsigned base_m = ((unsigned)i * Bb + (unsigned)b) * (unsigned)Pp;

  float vf[32];
  float best = -INFINITY;
#pragma unroll
  for (int c = 0; c < 32; ++c) {        // static unroll; uniform skip branch
    if (c < nchunk) {
      float2 aw = alds[c * 64 + lane];
      unsigned b0, b1;
      tf2x32(kr0, kr1, 0u, base_m + (unsigned)__float_as_int(aw.y), b0, b1);
      float v = __fadd_rn(gumbel_fast(b0 ^ b1), aw.x);
      vf[c] = v;
      best = fmaxf(best, v);
    } else {
      vf[c] = -INFINITY;
    }
  }
  for (int off = 1; off <= 32; off <<= 1)
    best = fmaxf(best, __shfl_xor(best, off));
  float cut = best - 0.125f;

  unsigned mask = 0u;                   // candidate chunks for this lane
#pragma unroll
  for (int c = 0; c < 32; ++c)
    mask |= (vf[c] >= cut) ? (1u << c) : 0u;

  float bv = -INFINITY;
  int bj = 0x7fffffff;
  while (mask) {                        // ~1.1 candidates per sample
    int c = __builtin_ctz(mask);
    mask &= mask - 1u;
    float2 aw = alds[c * 64 + lane];
    int j = __float_as_int(aw.y);
    unsigned b0, b1;
    tf2x32(kr0, kr1, 0u, base_m + (unsigned)j, b0, b1);
    float v = __fadd_rn(gumbel_exact(b0 ^ b1), aw.x);
    if (v > bv || (v == bv && j < bj)) { bv = v; bj = j; }
  }
  for (int off = 1; off <= 32; off <<= 1) {   // lexicographic wave argmax
    float ov = __shfl_xor(bv, off);
    int   oj = __shfl_xor(bj, off);
    if (ov > bv || (ov == bv && oj < bj)) { bv = ov; bj = oj; }
  }
  if (lane == 0)
    ((int*)pseq)[(((size_t)b * Tt + t) * Pp + i) * Dd] = bj;
}

// ---------------------------------------------------------------------------
// Kernel C: resample-gather + linear-Gaussian forward + measurement logw.
// One thread per (b,p).  Reads idx from pseq[b,t,p,0] (written by cat), then
// overwrites that slot.  numpy pairwise-16 order for S and sum(log_r).
// ---------------------------------------------------------------------------
__global__ __launch_bounds__(256) void fwd_kernel(
    const float* __restrict__ prev,    // init_particles (t==0) or pseq
    float* __restrict__ pseq,
    float* __restrict__ wseq,
    const float* __restrict__ obs,
    const float* __restrict__ Amat,
    const float* __restrict__ bvec,
    const float* __restrict__ log_sigma,
    const float* __restrict__ Cmat,
    const float* __restrict__ log_r,
    int t) {
  int gid = blockIdx.x * 256 + threadIdx.x;   // b*P + p
  int b = gid >> 11;
  int p = gid & (Pp - 1);

  unsigned kt0, kt1, kn0, kn1;
  tf2x32(0u, 42u, 0u, (unsigned)t, kt0, kt1);
  tf2x32(kt0, kt1, 0u, 1u, kn0, kn1);         // split -> k_noise

  size_t slot = (((size_t)b * Tt + t) * Pp + p) * Dd;
  int src_p = ((const int*)pseq)[slot];       // stashed by cat_kernel
  const float* xsrc = (t == 0)
      ? (prev + ((size_t)b * Pp + src_p) * Dd)
      : (prev + (((size_t)b * Tt + (t - 1)) * Pp + src_p) * Dd);
  float x[Dd];
  for (int d = 0; d < Dd; ++d) x[d] = xsrc[d];

  float xn[Dd];
  unsigned base_m = ((unsigned)b * Pp + (unsigned)p) * (unsigned)Dd;
  for (int e = 0; e < Dd; ++e) {
    float acc = 0.f;                   // sequential-K fma chain
    for (int d = 0; d < Dd; ++d) acc = fmaf(x[d], Amat[e * Dd + d], acc);
    unsigned b0, b1;
    tf2x32(kn0, kn1, 0u, base_m + (unsigned)e, b0, b1);
    unsigned bits = b0 ^ b1;
    float fl = __uint_as_float(0x3f800000u | (bits >> 9)) - 1.0f;
    float u  = __fadd_rn(__fmul_rn(fl, 2.0f), -0x1.fffffep-1f);
    float n  = __fmul_rn(1.41421356f, erfinv_xla(u));
    xn[e] = __fadd_rn(__fadd_rn(acc, bvec[e]),
                      __fmul_rn(n, expf_cr(log_sigma[e])));
  }

  float* pdst = pseq + slot;
  for (int e = 0; e < Dd; ++e) pdst[e] = xn[e];

  const float* y = obs + ((size_t)b * Tt + t) * NOBS;
  float aa[NOBS];
  for (int o = 0; o < NOBS; ++o) {
    float macc = 0.f;
    for (int d = 0; d < Dd; ++d) macc = fmaf(xn[d], Cmat[o * Dd + d], macc);
    float r = __fmul_rn(__fsub_rn(y[o], macc), expf_cr(-log_r[o]));
    aa[o] = __fmul_rn(r, r);
  }
  // numpy pairwise n=16: r[j]=a[j]+a[j+8]; ((r0+r1)+(r2+r3))+((r4+r5)+(r6+r7))
  float r8[8], l8[8];
  for (int o = 0; o < 8; ++o) {
    r8[o] = __fadd_rn(aa[o], aa[o + 8]);
    l8[o] = __fadd_rn(log_r[o], log_r[o + 8]);
  }
  float S = __fadd_rn(
      __fadd_rn(__fadd_rn(r8[0], r8[1]), __fadd_rn(r8[2], r8[3])),
      __fadd_rn(__fadd_rn(r8[4], r8[5]), __fadd_rn(r8[6], r8[7])));
  float slr = __fadd_rn(
      __fadd_rn(__fadd_rn(l8[0], l8[1]), __fadd_rn(l8[2], l8[3])),
      __fadd_rn(__fadd_rn(l8[4], l8[5]), __fadd_rn(l8[6], l8[7])));
  // logw = (-0.5*S - slr) - 8.0f*fl32(log(2*pi))   (left-assoc, f32 steps)
  const float c_term = 8.0f * (float)1.8378770664093453;  // exact *8
  float logw = __fsub_rn(__fsub_rn(__fmul_rn(-0.5f, S), slr), c_term);
  wseq[((size_t)b * Tt + t) * Pp + p] = logw;
}

// ---------------------------------------------------------------------------
extern "C" void kernel_launch(void* const* d_in, const int* in_sizes, int n_in,
                              void* d_out, int out_size, void* d_ws, size_t ws_size,
                              hipStream_t stream) {
  (void)in_sizes; (void)n_in; (void)out_size; (void)ws_size;
  const float* obs       = (const float*)d_in[0];   // [B,T,NOBS]
  const float* init_p    = (const float*)d_in[1];   // [B,P,D]
  const float* Amat      = (const float*)d_in[2];   // [D,D]
  const float* bvec      = (const float*)d_in[3];   // [D]
  const float* log_sigma = (const float*)d_in[4];   // [D]
  const float* Cmat      = (const float*)d_in[5];   // [NOBS,D]
  const float* log_r     = (const float*)d_in[6];   // [NOBS]

  float* pseq = (float*)d_out;                      // [B,T,P,D]
  float* wseq = pseq + (size_t)Bb * Tt * Pp * Dd;   // [B,T,P,1]

  // Workspace: counts[32] @ +0 (pad to 256B), active lists [B][P] float2 after.
  int*    counts = (int*)d_ws;
  float2* act    = (float2*)((char*)d_ws + 256);    // 256 + 512KB used

  // Resample idx stashed in pseq[b,t,p,0]; normalized weights never hit HBM.
  for (int t = 0; t < Tt; ++t) {
    norm_kernel<<<Bb, 256, 0, stream>>>(wseq, act, counts, t);
    cat_kernel<<<dim3(Pp / 4, Bb), 256, 0, stream>>>(act, counts, pseq, t);
    fwd_kernel<<<(Bb * Pp) / 256, 256, 0, stream>>>(
        t == 0 ? init_p : pseq, pseq, wseq,
        obs, Amat, bvec, log_sigma, Cmat, log_r, t);
  }
}

// Round 2
// 23234.096 us; speedup vs baseline: 1.0165x; 1.0165x over previous
//
#include <hip/hip_runtime.h>
#include <math.h>

// Problem constants (fixed by the reference)
#define Bb 32
#define Tt 64
#define Pp 2048
#define Dd 32
#define NOBS 16

// Gumbel-max screen cut (normalized weights => Sum e^w ~= 1):
//   E[#candidates per sample] = e^{-CUT} ~= 10
//   P(fallback per wave)      = exp(-e^{-CUT}) ~= 4.5e-5
#define CUTF (-2.3f)

// ---------------------------------------------------------------------------
// Threefry-2x32-20 (exact JAX semantics, threefry_partitionable=True default):
//   base  = key(42)            -> (0, 42)
//   kt    = fold_in(base, t)   -> TF(base, (0, t))
//   k_res, k_noise = split(kt) -> TF(kt, (0,0)), TF(kt, (0,1))
//   draw i (32-bit)            -> x0 ^ x1 of TF(k, (hi32(i), lo32(i)))
// ---------------------------------------------------------------------------
__device__ __forceinline__ unsigned rotl32(unsigned v, int r) {
  return (v << r) | (v >> (32 - r));
}

__device__ __forceinline__ void tf2x32(unsigned k0, unsigned k1,
                                       unsigned c0, unsigned c1,
                                       unsigned& r0, unsigned& r1) {
  unsigned k2 = k0 ^ k1 ^ 0x1BD11BDAu;
  unsigned x0 = c0 + k0;
  unsigned x1 = c1 + k1;
#define TF_ROUND(R) { x0 += x1; x1 = rotl32(x1, (R)); x1 ^= x0; }
  TF_ROUND(13) TF_ROUND(15) TF_ROUND(26) TF_ROUND(6)
  x0 += k1; x1 += k2 + 1u;
  TF_ROUND(17) TF_ROUND(29) TF_ROUND(16) TF_ROUND(24)
  x0 += k2; x1 += k0 + 2u;
  TF_ROUND(13) TF_ROUND(15) TF_ROUND(26) TF_ROUND(6)
  x0 += k0; x1 += k1 + 3u;
  TF_ROUND(17) TF_ROUND(29) TF_ROUND(16) TF_ROUND(24)
  x0 += k1; x1 += k2 + 4u;
  TF_ROUND(13) TF_ROUND(15) TF_ROUND(26) TF_ROUND(6)
  x0 += k2; x1 += k0 + 5u;
#undef TF_ROUND
  r0 = x0; r1 = x1;
}

// Host copy for wave-uniform key derivation (hoisted out of the kernels).
static inline void tf2x32_host(unsigned k0, unsigned k1,
                               unsigned c0, unsigned c1,
                               unsigned& r0, unsigned& r1) {
  unsigned k2 = k0 ^ k1 ^ 0x1BD11BDAu;
  unsigned x0 = c0 + k0;
  unsigned x1 = c1 + k1;
#define TF_ROUND(R) { x0 += x1; x1 = (x1 << (R)) | (x1 >> (32 - (R))); x1 ^= x0; }
  TF_ROUND(13) TF_ROUND(15) TF_ROUND(26) TF_ROUND(6)
  x0 += k1; x1 += k2 + 1u;
  TF_ROUND(17) TF_ROUND(29) TF_ROUND(16) TF_ROUND(24)
  x0 += k2; x1 += k0 + 2u;
  TF_ROUND(13) TF_ROUND(15) TF_ROUND(26) TF_ROUND(6)
  x0 += k0; x1 += k1 + 3u;
  TF_ROUND(17) TF_ROUND(29) TF_ROUND(16) TF_ROUND(24)
  x0 += k1; x1 += k2 + 4u;
  TF_ROUND(13) TF_ROUND(15) TF_ROUND(26) TF_ROUND(6)
  x0 += k2; x1 += k0 + 5u;
#undef TF_ROUND
  r0 = x0; r1 = x1;
}

// Correctly-rounded f32 log/exp via double libm.
__device__ __forceinline__ float logf_cr(float x) { return (float)log((double)x); }
__device__ __forceinline__ float expf_cr(float x) { return (float)exp((double)x); }

// Exact gumbel, bit-faithful to jax.random.gumbel:
// u = bitcast(bits>>9 | 1.0f) - 1; u = max(tiny, u); g = -ln(-ln u)
// Hard range (all 2^23 mantissas): g in [-4.46967, +15.94239].
__device__ __forceinline__ float gumbel_exact(unsigned bits) {
  float fl = __uint_as_float(0x3f800000u | (bits >> 9)) - 1.0f;  // exact
  float u  = __fadd_rn(fl, 1.17549435e-38f);
  float il = logf_cr(u);             // in [-87.34, -5.96e-8], never 0
  return -logf_cr(-il);
}

// XLA ErfInv32 (Giles poly) with XLA EmitLog1p (|x|<1e-4 small branch).
__device__ __forceinline__ float erfinv_xla(float x) {
  float nxx = __fmul_rn(-x, x);
  float l1p;
  if (fabsf(nxx) < 1e-4f) {
    l1p = __fmul_rn(__fadd_rn(__fmul_rn(-0.5f, nxx), 1.0f), nxx);
  } else {
    l1p = logf_cr(__fadd_rn(1.0f, nxx));
  }
  float w = -l1p;
  float p;
  if (w < 5.0f) {
    float ww = __fsub_rn(w, 2.5f);
    p = 2.81022636e-08f;
    p = __fadd_rn(3.43273939e-07f,  __fmul_rn(p, ww));
    p = __fadd_rn(-3.5233877e-06f,  __fmul_rn(p, ww));
    p = __fadd_rn(-4.39150654e-06f, __fmul_rn(p, ww));
    p = __fadd_rn(0.00021858087f,   __fmul_rn(p, ww));
    p = __fadd_rn(-0.00125372503f,  __fmul_rn(p, ww));
    p = __fadd_rn(-0.00417768164f,  __fmul_rn(p, ww));
    p = __fadd_rn(0.246640727f,     __fmul_rn(p, ww));
    p = __fadd_rn(1.50140941f,      __fmul_rn(p, ww));
  } else {
    float ww = __fsub_rn(sqrtf(w), 3.0f);
    p = -0.000200214257f;
    p = __fadd_rn(0.000100950558f,  __fmul_rn(p, ww));
    p = __fadd_rn(0.00134934322f,   __fmul_rn(p, ww));
    p = __fadd_rn(-0.00367342844f,  __fmul_rn(p, ww));
    p = __fadd_rn(0.00573950773f,   __fmul_rn(p, ww));
    p = __fadd_rn(-0.0076224613f,   __fmul_rn(p, ww));
    p = __fadd_rn(0.00943887047f,   __fmul_rn(p, ww));
    p = __fadd_rn(1.00167406f,      __fmul_rn(p, ww));
    p = __fadd_rn(2.83297682f,      __fmul_rn(p, ww));
  }
  return __fmul_rn(p, x);
}

// ---------------------------------------------------------------------------
// Kernel A: logsumexp (exact numpy pairwise order) + per-particle u-space
// screen thresholds.  Candidate test for cat's pass 1 must satisfy:
//   v_f32 = fadd(gumbel_exact(bits), wn_j) >= CUTF  ==>  bits >= V_j.
// Derivation: v >= cut <=> u >= U_j := F(cut - w_j) = exp(-exp(-(cut-w_j)))
// (g monotone increasing in u).  Conservative slack 1e-4 in u-space covers
// all f32/CR rounding (min |dg/du| = e => g-margin >= 2.7e-4 >> ~1e-5 error).
// Integer form: fl = (bits>>9)*2^-23, so  fl >= Um  <=>  bits >= (ceil(Um*2^23))<<9.
// ---------------------------------------------------------------------------
__global__ __launch_bounds__(256) void norm_kernel(const float* __restrict__ wseq,
                                                   float* __restrict__ wn_out,
                                                   unsigned* __restrict__ vs_out,
                                                   int t) {
  __shared__ float lw[Pp];
  __shared__ float red[256];
  __shared__ float rr[128];
  __shared__ float sh_mx, sh_lse;
  int b = blockIdx.x;
  int tid = threadIdx.x;
  const float* src = wseq + ((size_t)b * Tt + (t - 1)) * Pp;  // valid t>0
  float loc[8];
  for (int k = 0; k < 8; ++k) {
    int j = tid + k * 256;
    float v = (t == 0) ? 0.00048828125f : src[j];   // w0 = 1/2048
    lw[j] = v; loc[k] = v;
  }
  float m = loc[0];
  for (int k = 1; k < 8; ++k) m = fmaxf(m, loc[k]);
  red[tid] = m;
  __syncthreads();
  if (tid == 0) {                      // max is order-free; keep it simple
    float mm = red[0];
    for (int k = 1; k < 256; ++k) mm = fmaxf(mm, red[k]);
    sh_mx = mm;
  }
  __syncthreads();
  float mx = sh_mx;
  if (tid < 128) {                     // numpy leaf chains (16 terms, seq)
    int base = (tid >> 3) * 128 + (tid & 7);
    float r = expf_cr(__fsub_rn(lw[base], mx));
    for (int i = 1; i < 16; ++i)
      r = __fadd_rn(r, expf_cr(__fsub_rn(lw[base + 8 * i], mx)));
    rr[tid] = r;
  }
  __syncthreads();
  if (tid < 64) {                      // adjacent binary tree (exact order)
    float s = __fadd_rn(rr[2 * tid], rr[2 * tid + 1]);
    for (int off = 1; off <= 32; off <<= 1)
      s = __fadd_rn(s, __shfl_xor(s, off));   // commutative -> same bits
    if (tid == 0) sh_lse = __fadd_rn(logf_cr(s), mx);
  }
  __syncthreads();
  float lse = sh_lse;
  float* wdst = wn_out + (size_t)b * Pp;
  unsigned* vdst = vs_out + (size_t)b * Pp;
  for (int k = 0; k < 8; ++k) {
    int j = tid + k * 256;
    float wn = fmaxf(__fsub_rn(lw[j], lse), -50.0f);
    wdst[j] = wn;
    double g_req = (double)CUTF - (double)wn;      // required gumbel
    double U  = exp(-exp(-g_req));                 // Gumbel CDF at g_req
    double Um = U - 1e-4;                          // conservative slack
    unsigned V;
    if (!(Um > 0.0)) {
      V = 0u;                                      // always candidate
    } else {
      double mth = ceil(Um * 8388608.0);           // 2^23
      // mth == 2^23 -> unreachable by any fl; saturate (false pos only at
      // bits==0xFFFFFFFF, rate 2^-32, harmless: pass 2 is exact anyway).
      V = (mth >= 8388608.0) ? 0xFFFFFFFFu : (((unsigned)mth) << 9);
    }
    vdst[j] = V;
  }
}

// ---------------------------------------------------------------------------
// Kernel B: jax.random.categorical(k_res, w, shape=(P,B)).T — gumbel shape
// (P,B,P), flat m=(i*B+b)*P+j, argmax over j, first-occurrence ties.
// One wave per sample i.  Pass 1: pure-integer screen (hash + 1 compare per
// pair, NO transcendentals, no per-chunk float state -> small rolled body).
// Pass 2: exact CR eval of the ~10 candidates per wave; if the wave best
// < CUTF (incl. empty; wave-uniform after reduction) the screen guarantee
// doesn't apply -> rare exact full rescan (rate ~4.5e-5 per wave).
// Result idx stashed as int bits in pseq[b,t,i,0].
// ---------------------------------------------------------------------------
__global__ __launch_bounds__(256) void cat_kernel(const float* __restrict__ wn_ws,
                                                  const unsigned* __restrict__ vs_ws,
                                                  float* __restrict__ pseq,
                                                  int t, unsigned kr0, unsigned kr1) {
  __shared__ float wlds[Pp];
  __shared__ unsigned vlds[Pp];
  int b = blockIdx.y;
  int tid = threadIdx.x;
  const float*    wsrc = wn_ws + (size_t)b * Pp;
  const unsigned* vsrc = vs_ws + (size_t)b * Pp;
  for (int k = 0; k < Pp / 256; ++k) {
    wlds[tid + k * 256] = wsrc[tid + k * 256];
    vlds[tid + k * 256] = vsrc[tid + k * 256];
  }
  __syncthreads();

  int wave = tid >> 6, lane = tid & 63;
  int i = blockIdx.x * 4 + wave;
  unsigned base_m = ((unsigned)i * Bb + (unsigned)b) * (unsigned)Pp;

  unsigned mask = 0u;                  // candidate chunks for this lane
#pragma unroll 4
  for (int c = 0; c < 32; ++c) {
    unsigned b0, b1;
    tf2x32(kr0, kr1, 0u, base_m + (unsigned)(c * 64 + lane), b0, b1);
    unsigned bits = b0 ^ b1;
    if (bits >= vlds[c * 64 + lane]) mask |= (1u << c);
  }

  float bv = -INFINITY;
  int bj = 0x7fffffff;
  while (mask) {                       // ~10 candidates per wave total
    int c = __builtin_ctz(mask);
    mask &= mask - 1u;
    int j = c * 64 + lane;             // ascending j within lane
    unsigned b0, b1;
    tf2x32(kr0, kr1, 0u, base_m + (unsigned)j, b0, b1);
    float v = __fadd_rn(gumbel_exact(b0 ^ b1), wlds[j]);
    if (v > bv || (v == bv && j < bj)) { bv = v; bj = j; }
  }
  for (int off = 1; off <= 32; off <<= 1) {   // lexicographic wave argmax
    float ov = __shfl_xor(bv, off);
    int   oj = __shfl_xor(bj, off);
    if (ov > bv || (ov == bv && oj < bj)) { bv = ov; bj = oj; }
  }

  if (!(bv >= CUTF)) {                 // wave-uniform; guarantees void -> rescan
    bv = -INFINITY; bj = 0x7fffffff;
    for (int c = 0; c < 32; ++c) {
      int j = c * 64 + lane;
      unsigned b0, b1;
      tf2x32(kr0, kr1, 0u, base_m + (unsigned)j, b0, b1);
      float v = __fadd_rn(gumbel_exact(b0 ^ b1), wlds[j]);
      if (v > bv || (v == bv && j < bj)) { bv = v; bj = j; }
    }
    for (int off = 1; off <= 32; off <<= 1) {
      float ov = __shfl_xor(bv, off);
      int   oj = __shfl_xor(bj, off);
      if (ov > bv || (ov == bv && oj < bj)) { bv = ov; bj = oj; }
    }
  }

  if (lane == 0)
    ((int*)pseq)[(((size_t)b * Tt + t) * Pp + i) * Dd] = bj;
}

// ---------------------------------------------------------------------------
// Kernel C: resample-gather + linear-Gaussian forward + measurement logw.
// One thread per (b,p).  Reads idx from pseq[b,t,p,0] (written by cat), then
// overwrites that slot.  numpy pairwise-16 order for S and sum(log_r).
// ---------------------------------------------------------------------------
__global__ __launch_bounds__(256) void fwd_kernel(
    const float* __restrict__ prev,    // init_particles (t==0) or pseq
    float* __restrict__ pseq,
    float* __restrict__ wseq,
    const float* __restrict__ obs,
    const float* __restrict__ Amat,
    const float* __restrict__ bvec,
    const float* __restrict__ log_sigma,
    const float* __restrict__ Cmat,
    const float* __restrict__ log_r,
    int t, unsigned kn0, unsigned kn1) {
  int gid = blockIdx.x * 256 + threadIdx.x;   // b*P + p
  int b = gid >> 11;
  int p = gid & (Pp - 1);

  size_t slot = (((size_t)b * Tt + t) * Pp + p) * Dd;
  int src_p = ((const int*)pseq)[slot];       // stashed by cat_kernel
  const float* xsrc = (t == 0)
      ? (prev + ((size_t)b * Pp + src_p) * Dd)
      : (prev + (((size_t)b * Tt + (t - 1)) * Pp + src_p) * Dd);
  float x[Dd];
  for (int d = 0; d < Dd; ++d) x[d] = xsrc[d];

  float xn[Dd];
  unsigned base_m = ((unsigned)b * Pp + (unsigned)p) * (unsigned)Dd;
  for (int e = 0; e < Dd; ++e) {
    float acc = 0.f;                   // sequential-K fma chain
    for (int d = 0; d < Dd; ++d) acc = fmaf(x[d], Amat[e * Dd + d], acc);
    unsigned b0, b1;
    tf2x32(kn0, kn1, 0u, base_m + (unsigned)e, b0, b1);
    unsigned bits = b0 ^ b1;
    float fl = __uint_as_float(0x3f800000u | (bits >> 9)) - 1.0f;
    float u  = __fadd_rn(__fmul_rn(fl, 2.0f), -0x1.fffffep-1f);
    float n  = __fmul_rn(1.41421356f, erfinv_xla(u));
    xn[e] = __fadd_rn(__fadd_rn(acc, bvec[e]),
                      __fmul_rn(n, expf_cr(log_sigma[e])));
  }

  float* pdst = pseq + slot;
  for (int e = 0; e < Dd; ++e) pdst[e] = xn[e];

  const float* y = obs + ((size_t)b * Tt + t) * NOBS;
  float aa[NOBS];
  for (int o = 0; o < NOBS; ++o) {
    float macc = 0.f;
    for (int d = 0; d < Dd; ++d) macc = fmaf(xn[d], Cmat[o * Dd + d], macc);
    float r = __fmul_rn(__fsub_rn(y[o], macc), expf_cr(-log_r[o]));
    aa[o] = __fmul_rn(r, r);
  }
  // numpy pairwise n=16: r[j]=a[j]+a[j+8]; ((r0+r1)+(r2+r3))+((r4+r5)+(r6+r7))
  float r8[8], l8[8];
  for (int o = 0; o < 8; ++o) {
    r8[o] = __fadd_rn(aa[o], aa[o + 8]);
    l8[o] = __fadd_rn(log_r[o], log_r[o + 8]);
  }
  float S = __fadd_rn(
      __fadd_rn(__fadd_rn(r8[0], r8[1]), __fadd_rn(r8[2], r8[3])),
      __fadd_rn(__fadd_rn(r8[4], r8[5]), __fadd_rn(r8[6], r8[7])));
  float slr = __fadd_rn(
      __fadd_rn(__fadd_rn(l8[0], l8[1]), __fadd_rn(l8[2], l8[3])),
      __fadd_rn(__fadd_rn(l8[4], l8[5]), __fadd_rn(l8[6], l8[7])));
  // logw = (-0.5*S - slr) - 8.0f*fl32(log(2*pi))   (left-assoc, f32 steps)
  const float c_term = 8.0f * (float)1.8378770664093453;  // exact *8
  float logw = __fsub_rn(__fsub_rn(__fmul_rn(-0.5f, S), slr), c_term);
  wseq[((size_t)b * Tt + t) * Pp + p] = logw;
}

// ---------------------------------------------------------------------------
extern "C" void kernel_launch(void* const* d_in, const int* in_sizes, int n_in,
                              void* d_out, int out_size, void* d_ws, size_t ws_size,
                              hipStream_t stream) {
  (void)in_sizes; (void)n_in; (void)out_size; (void)ws_size;
  const float* obs       = (const float*)d_in[0];   // [B,T,NOBS]
  const float* init_p    = (const float*)d_in[1];   // [B,P,D]
  const float* Amat      = (const float*)d_in[2];   // [D,D]
  const float* bvec      = (const float*)d_in[3];   // [D]
  const float* log_sigma = (const float*)d_in[4];   // [D]
  const float* Cmat      = (const float*)d_in[5];   // [NOBS,D]
  const float* log_r     = (const float*)d_in[6];   // [NOBS]

  float* pseq = (float*)d_out;                      // [B,T,P,D]
  float* wseq = pseq + (size_t)Bb * Tt * Pp * Dd;   // [B,T,P,1]

  // Workspace: wn [B][P] float @ +0 (256KB), vs [B][P] uint @ +256KB.
  float*    wn = (float*)d_ws;
  unsigned* vs = (unsigned*)((char*)d_ws + (size_t)Bb * Pp * 4);

  // Resample idx stashed in pseq[b,t,p,0]; normalized weights never hit HBM
  // output; keys derived on host (wave-uniform).
  for (int t = 0; t < Tt; ++t) {
    unsigned kt0, kt1, kr0, kr1, kn0, kn1;
    tf2x32_host(0u, 42u, 0u, (unsigned)t, kt0, kt1);  // fold_in(key(42), t)
    tf2x32_host(kt0, kt1, 0u, 0u, kr0, kr1);          // split -> k_res
    tf2x32_host(kt0, kt1, 0u, 1u, kn0, kn1);          // split -> k_noise

    norm_kernel<<<Bb, 256, 0, stream>>>(wseq, wn, vs, t);
    cat_kernel<<<dim3(Pp / 4, Bb), 256, 0, stream>>>(wn, vs, pseq, t, kr0, kr1);
    fwd_kernel<<<(Bb * Pp) / 256, 256, 0, stream>>>(
        t == 0 ? init_p : pseq, pseq, wseq,
        obs, Amat, bvec, log_sigma, Cmat, log_r, t, kn0, kn1);
  }
}